// Round 9
// baseline (121.245 us; speedup 1.0000x reference)
//
#include <hip/hip_runtime.h>
#include <hip/hip_bf16.h>

// Problem constants (match reference)
#define B 8
#define S 2048
#define N 512
#define D 1024
#define MAX_W 32
#define MASK_FILL -1000.0f

// native clang vector type — required by __builtin_nontemporal_store
typedef float vfloat4 __attribute__((ext_vector_type(4)));

// fp32 -> bf16 with round-to-nearest-even (inputs are finite random normals)
__device__ inline unsigned short f2bf(float f) {
    unsigned u = __float_as_uint(f);
    u += 0x7fff + ((u >> 16) & 1);
    return (unsigned short)(u >> 16);
}

// ---------------------------------------------------------------------------
// Kernel 1 (prep): logits + bf16 compression of seq, one pass over seq.
//   logits[b,s] = dot(seq[b,s,:], att_w) + att_b   (fp32)
//   seqh = bf16(seq): pool working set per batch = 4 MiB = one XCD L2.
//
// XCD-affine block mapping (R9): blockIdx & 7 selects the batch, matching
// pool_kernel's mapping. Batch b's compressed rows and logits are produced
// on XCD b and stay dirty/resident in that XCD's 4 MiB L2 across the launch
// boundary (end-of-kernel release drains to L2, the coherence point), so
// pool's gathers become L2 hits instead of L3 round-trips. R8 wrote them
// linearly -> scattered over all 8 XCD L2s -> pool first-touch missed to L3.
// Pure permutation; coalescing unchanged; correctness mapping-independent.
// ---------------------------------------------------------------------------
__global__ __launch_bounds__(512) void prep_kernel(
    const float* __restrict__ seq,
    const float* __restrict__ att_w,
    const float* __restrict__ att_b,
    float* __restrict__ logits,
    unsigned short* __restrict__ seqh)
{
    const int b    = blockIdx.x & 7;                 // batch -> XCD affinity
    const int grp  = blockIdx.x >> 3;                // 0..255 within batch
    const int row  = b * S + grp * 8 + (threadIdx.x >> 6);  // 8 waves/block
    const int lane = threadIdx.x & 63;

    const float4* rp = (const float4*)(seq + (size_t)row * D);
    const float4* wp = (const float4*)att_w;

    float4 a[4];
    float acc = 0.0f;
#pragma unroll
    for (int k = 0; k < 4; ++k) {
        a[k] = rp[lane + 64 * k];
        const float4 w = wp[lane + 64 * k];
        acc += a[k].x * w.x + a[k].y * w.y + a[k].z * w.z + a[k].w * w.w;
    }

    // compressed row: ushort4 stores, 8 B/lane, coalesced
    ushort4* hp = (ushort4*)(seqh + (size_t)row * D);
#pragma unroll
    for (int k = 0; k < 4; ++k) {
        ushort4 h;
        h.x = f2bf(a[k].x); h.y = f2bf(a[k].y);
        h.z = f2bf(a[k].z); h.w = f2bf(a[k].w);
        hp[lane + 64 * k] = h;
    }

#pragma unroll
    for (int off = 32; off > 0; off >>= 1)
        acc += __shfl_down(acc, off);
    if (lane == 0)
        logits[row] = acc + att_b[0];
}

// ---------------------------------------------------------------------------
// Kernel 2: per-span masked softmax + pooling over bf16 rows.
// One block (256 threads) per span (4096 blocks -> full occupancy). Thread
// tid owns cols [4*tid, 4*tid+4): one 8 B (uint2 = 4 bf16) load per row,
// fully coalesced. blockIdx & 7 -> batch: reads hit the same XCD L2 that
// prep populated.
//
// Softmax in fp32 from fp32 logits: masked entries get weight exactly 0
// (expf(-1000-m)==0 in fp32, identical to the reference), s_idx clamped,
// so the 4-padded loop is reference-identical in structure; the only
// numeric delta vs reference is bf16 quantization of the pooled values.
// ---------------------------------------------------------------------------
__global__ __launch_bounds__(256) void pool_kernel(
    const unsigned short* __restrict__ seqh,
    const int*   __restrict__ spans,
    const float* __restrict__ logits,
    float* __restrict__ out)
{
    const int b    = blockIdx.x & 7;        // batch -> XCD affinity
    const int n    = blockIdx.x >> 3;       // span within batch
    const int span = b * N + n;

    const int start = spans[2 * span + 0];
    const int end   = spans[2 * span + 1];  // inclusive
    const int width = end - start;          // valid entries = width + 1

    __shared__ float s_attn[MAX_W];
    __shared__ int   s_idx[MAX_W];

    const int tid = threadIdx.x;

    if (tid < MAX_W) {
        const int w   = tid;
        const int raw = end - w;
        const bool valid = (w <= width) && (raw >= 0);
        const int idx = raw > 0 ? raw : 0;
        const float l = valid ? logits[b * S + idx] : MASK_FILL;

        float m = l;
#pragma unroll
        for (int off = 16; off > 0; off >>= 1)
            m = fmaxf(m, __shfl_down(m, off, 32));
        m = __shfl(m, 0, 32);

        const float p = __expf(l - m);

        float sum = p;
#pragma unroll
        for (int off = 16; off > 0; off >>= 1)
            sum += __shfl_down(sum, off, 32);
        sum = __shfl(sum, 0, 32);

        s_attn[w] = p / sum;                // exactly 0 for masked entries
        s_idx[w]  = idx;
    }
    __syncthreads();

    const unsigned short* sb = seqh + (size_t)b * S * D;

    float4 acc = make_float4(0.f, 0.f, 0.f, 0.f);

    const int cnt  = width + 1;             // wave-uniform per block
    const int cnt4 = (cnt + 3) & ~3;        // <= 32

    for (int w = 0; w < cnt4; w += 4) {
        const float a0 = s_attn[w + 0];
        const float a1 = s_attn[w + 1];
        const float a2 = s_attn[w + 2];
        const float a3 = s_attn[w + 3];
        const int   i0 = s_idx[w + 0];
        const int   i1 = s_idx[w + 1];
        const int   i2 = s_idx[w + 2];
        const int   i3 = s_idx[w + 3];

        // 4 independent 8 B loads in flight (4 bf16 each)
        const uint2 q0 = ((const uint2*)(sb + (size_t)i0 * D))[tid];
        const uint2 q1 = ((const uint2*)(sb + (size_t)i1 * D))[tid];
        const uint2 q2 = ((const uint2*)(sb + (size_t)i2 * D))[tid];
        const uint2 q3 = ((const uint2*)(sb + (size_t)i3 * D))[tid];

        // unpack: low ushort = even col, high ushort = odd col
#define BL(u) __uint_as_float((u) << 16)
#define BH(u) __uint_as_float((u) & 0xffff0000u)
        acc.x += a0 * BL(q0.x) + a1 * BL(q1.x) + a2 * BL(q2.x) + a3 * BL(q3.x);
        acc.y += a0 * BH(q0.x) + a1 * BH(q1.x) + a2 * BH(q2.x) + a3 * BH(q3.x);
        acc.z += a0 * BL(q0.y) + a1 * BL(q1.y) + a2 * BL(q2.y) + a3 * BL(q3.y);
        acc.w += a0 * BH(q0.y) + a1 * BH(q1.y) + a2 * BH(q2.y) + a3 * BH(q3.y);
#undef BL
#undef BH
    }

    // streaming output: non-temporal store, keep L2 for seqh
    vfloat4 va;
    va.x = acc.x; va.y = acc.y; va.z = acc.z; va.w = acc.w;
    vfloat4* op = ((vfloat4*)(out + (size_t)span * D)) + tid;
    __builtin_nontemporal_store(va, op);
}

// ---------------------------------------------------------------------------
extern "C" void kernel_launch(void* const* d_in, const int* in_sizes, int n_in,
                              void* d_out, int out_size, void* d_ws, size_t ws_size,
                              hipStream_t stream)
{
    const float* seq    = (const float*)d_in[0];  // (B,S,D) f32
    const int*   spans  = (const int*)  d_in[1];  // (B,N,2) i32
    const float* att_w  = (const float*)d_in[2];  // (D,1)   f32
    const float* att_b  = (const float*)d_in[3];  // (1,)    f32

    float* out    = (float*)d_out;                // (B,N,D) f32
    float* logits = (float*)d_ws;                 // (B,S)   f32   (64 KB)
    unsigned short* seqh =
        (unsigned short*)((char*)d_ws + (size_t)B * S * sizeof(float)); // 32 MB

    prep_kernel<<<(B * S) / 8, 512, 0, stream>>>(seq, att_w, att_b,
                                                 logits, seqh);
    pool_kernel<<<B * N, 256, 0, stream>>>(seqh, spans, logits, out);
}